// Round 9
// baseline (2386.462 us; speedup 1.0000x reference)
//
#include <hip/hip_runtime.h>

typedef __attribute__((ext_vector_type(8))) short s16x8;
typedef __attribute__((ext_vector_type(4))) short s16x4;
typedef __attribute__((ext_vector_type(4))) float f32x4;
typedef __attribute__((ext_vector_type(4))) unsigned short u16x4;

template<int V> struct IC { static constexpr int v = V; };

__device__ __forceinline__ unsigned short f2bf(float f){
  unsigned u = __float_as_uint(f);
  u += 0x7fffu + ((u >> 16) & 1u);   // RNE
  return (unsigned short)(u >> 16);
}

// async global->LDS, 16B per lane. LDS dst must be wave-uniform base (+lane*16 implicit).
__device__ __forceinline__ void gload16(const void* g, void* l){
  __builtin_amdgcn_global_load_lds((const __attribute__((address_space(1))) void*)g,
                                   (__attribute__((address_space(3))) void*)l, 16, 0, 0);
}

// x0 [16384,256] f32 -> XT [256,16384] bf16
__global__ void xpose_cvt(const float* __restrict__ src, unsigned short* __restrict__ dst){
  __shared__ float tile[64][65];
  const int R0 = blockIdx.x * 64;
  const int C0 = blockIdx.y * 64;
  const int t = threadIdx.x;
  #pragma unroll
  for (int i = 0; i < 16; ++i){
    int id = i * 256 + t; int r = id >> 6, c = id & 63;
    tile[r][c] = src[(size_t)(R0 + r) * 256 + (C0 + c)];
  }
  __syncthreads();
  #pragma unroll
  for (int i = 0; i < 16; ++i){
    int id = i * 256 + t; int c = id >> 6, r = id & 63;
    dst[(size_t)(C0 + c) * 16384 + (R0 + r)] = f2bf(tile[r][c]);
  }
}

__global__ void cvt_k(const float* __restrict__ src, unsigned short* __restrict__ dst, int n){
  int i = (blockIdx.x * 256 + threadIdx.x) * 4;
  if (i + 3 < n){
    f32x4 v = *(const f32x4*)(src + i);
    u16x4 o; o[0] = f2bf(v[0]); o[1] = f2bf(v[1]); o[2] = f2bf(v[2]); o[3] = f2bf(v[3]);
    *(u16x4*)(dst + i) = o;
  }
}

// ---------------- Big GEMM: P[kc] = A[16384,16384] @ X^T  (split-K=4) ----------------
// m97 structure: single-buffered LDS (A 16K + B 32K = 48 KiB), BM=128/BN=256/BK=64,
// 512 thr (8 waves 2m x 4n, wave tile 64x64), grid 512 -> 2 blocks/CU anti-phase.
// Staging via global_load_lds(16B): LDS linear, XOR swizzle applied on the GLOBAL
// source address; compute reads with the same XOR.
// Grid: xcd = b&7; kc = xcd>>1 (B-slice 2 MiB/XCD); mi = (xcd&1)*64 + (b>>3).
// AMODE: 0 = A fp32 reg-staged (convert + persist bf16 to Aout), 1 = A bf16 via DMA.
template<int AMODE>
__global__ __launch_bounds__(512, 4)
void gemmA_k(const void* __restrict__ Asrc, const unsigned short* __restrict__ Bsrc,
             float* __restrict__ Pdst, unsigned short* __restrict__ Aout)
{
  __shared__ __align__(16) unsigned short Alds[128 * 64];
  __shared__ __align__(16) unsigned short Blds[256 * 64];

  const int tid  = threadIdx.x;
  const int lane = tid & 63;
  const int wv   = tid >> 6;
  const int wm   = wv >> 2;        // 0..1 (64 rows each)
  const int wn   = wv & 3;         // 0..3 (64 cols each)
  const int fr = lane & 15, fq = lane >> 4;

  const int b    = blockIdx.x;
  const int xcd  = b & 7;
  const int kc   = xcd >> 1;                    // 0..3
  const int mi   = ((xcd & 1) << 6) + (b >> 3); // 0..127
  const int row0 = mi * 128;
  const int kbase = kc * 4096;

  const int srow = lane >> 3;
  const int scol = (lane & 7) ^ srow;

  const unsigned short* Bg = Bsrc + (size_t)(wv * 32 + srow) * 16384 + kbase + scol * 8;
  unsigned short* Bl = &Blds[wv * 2048 + lane * 8];
  const unsigned short* Ag = (AMODE == 1)
    ? (const unsigned short*)Asrc + (size_t)(row0 + wv * 16 + srow) * 16384 + kbase + scol * 8
    : nullptr;
  unsigned short* Al = &Alds[wv * 1024 + lane * 8];

  const int rS = tid >> 3;         // 0..63
  const int cS = tid & 7;
  const float* Af32 = (const float*)Asrc;

  f32x4 acc[4][4];
  #pragma unroll
  for (int m = 0; m < 4; ++m)
    #pragma unroll
    for (int n = 0; n < 4; ++n)
      acc[m][n] = f32x4{0.f, 0.f, 0.f, 0.f};

  #pragma unroll 1
  for (int s = 0; s < 64; ++s){
    const int k0 = kbase + s * 64;
    if constexpr (AMODE == 0){
      const float* pa = Af32 + (size_t)(row0 + rS) * 16384 + k0 + cS * 8;
      const float* pb = pa + (size_t)64 * 16384;
      f32x4 a0 = __builtin_nontemporal_load((const f32x4*)pa);
      f32x4 a1 = __builtin_nontemporal_load((const f32x4*)(pa + 4));
      f32x4 a2 = __builtin_nontemporal_load((const f32x4*)pb);
      f32x4 a3 = __builtin_nontemporal_load((const f32x4*)(pb + 4));
      #pragma unroll
      for (int i = 0; i < 4; ++i)
        gload16(Bg + (size_t)i * 8 * 16384 + s * 64, Bl + i * 512);
      s16x8 w0, w1;
      #pragma unroll
      for (int e = 0; e < 4; ++e){
        w0[e] = (short)f2bf(a0[e]); w0[e + 4] = (short)f2bf(a1[e]);
        w1[e] = (short)f2bf(a2[e]); w1[e + 4] = (short)f2bf(a3[e]);
      }
      *(s16x8*)&Alds[rS * 64 + ((cS ^ (rS & 7)) * 8)] = w0;
      *(s16x8*)&Alds[(rS + 64) * 64 + ((cS ^ (rS & 7)) * 8)] = w1;
      __builtin_nontemporal_store(w0, (s16x8*)&Aout[(size_t)(row0 + rS) * 16384 + k0 + cS * 8]);
      __builtin_nontemporal_store(w1, (s16x8*)&Aout[(size_t)(row0 + rS + 64) * 16384 + k0 + cS * 8]);
    } else {
      gload16(Ag + s * 64, Al);
      gload16(Ag + (size_t)8 * 16384 + s * 64, Al + 512);
      #pragma unroll
      for (int i = 0; i < 4; ++i)
        gload16(Bg + (size_t)i * 8 * 16384 + s * 64, Bl + i * 512);
    }
    __syncthreads();

    #pragma unroll
    for (int k = 0; k < 2; ++k){
      s16x8 af[4], bfr[4];
      const int c = k * 4 + fq;
      #pragma unroll
      for (int m = 0; m < 4; ++m){
        int row = wm * 64 + m * 16 + fr;
        af[m] = *(const s16x8*)&Alds[row * 64 + ((c ^ (row & 7)) * 8)];
      }
      #pragma unroll
      for (int n = 0; n < 4; ++n){
        int col = wn * 64 + n * 16 + fr;
        bfr[n] = *(const s16x8*)&Blds[col * 64 + ((c ^ (col & 7)) * 8)];
      }
      #pragma unroll
      for (int m = 0; m < 4; ++m)
        #pragma unroll
        for (int n = 0; n < 4; ++n)
          acc[m][n] = __builtin_amdgcn_mfma_f32_16x16x32_bf16(af[m], bfr[n], acc[m][n], 0, 0, 0);
    }
    __syncthreads();
  }

  float* P = Pdst + (size_t)kc * 16384 * 256;
  #pragma unroll
  for (int m = 0; m < 4; ++m){
    int rowb = row0 + wm * 64 + m * 16 + fq * 4;
    #pragma unroll
    for (int n = 0; n < 4; ++n){
      int col = wn * 64 + n * 16 + fr;
      #pragma unroll
      for (int j = 0; j < 4; ++j)
        __builtin_nontemporal_store(acc[m][n][j], &P[(size_t)(rowb + j) * 256 + col]);
    }
  }
}

// ---------------- Small GEMM: C[M,BN] = A[M,Kd] @ B^T, BM=32 ----------------
// AMODE: 1 = A bf16 | 2 = A bf16 + gather | 3 = A = sum of 4 fp32 partials
// EPI: 1 = bias+relu bf16 TRANSPOSED | 2 = bias+relu bf16 row-major | 3 = bias+relu fp32
template<int BN, int AMODE, int EPI>
__global__ __launch_bounds__(512, 2)
void gemm_k(const void* __restrict__ Asrc, const unsigned short* __restrict__ Bsrc,
            const float* __restrict__ bias, const int* __restrict__ gidx,
            void* __restrict__ Cdst, const int M, const int Kd)
{
  constexpr int NF = BN / 64;
  constexpr int BITER = BN / 64;
  __shared__ __align__(16) unsigned short Alds[2][32 * 64];
  __shared__ __align__(16) unsigned short Blds[2][BN * 64];

  const int tid  = threadIdx.x;
  const int lane = tid & 63;
  const int wv   = tid >> 6;
  const int wm   = wv >> 2;
  const int wn   = wv & 3;
  const int row0 = blockIdx.x * 32;
  const int fr = lane & 15, fq = lane >> 4;

  const int rA = tid >> 4;         // 0..31
  const int cA = tid & 15;         // 4-elem chunk along K
  const int rB = tid >> 3;         // 0..63
  const int cB = tid & 7;          // 8-elem chunk along K

  size_t arow;
  if (AMODE == 2) arow = (size_t)gidx[row0 + rA];
  else            arow = (size_t)(row0 + rA);

  f32x4 acc[NF];
  #pragma unroll
  for (int n = 0; n < NF; ++n) acc[n] = f32x4{0.f, 0.f, 0.f, 0.f};

  f32x4 aP[2][4]; s16x4 aB[2]; s16x8 bRg[2][BITER];

  auto loadAB = [&](auto rsc, int k0){
    constexpr int RS = decltype(rsc)::v;
    if constexpr (AMODE == 3){
      #pragma unroll
      for (int q = 0; q < 4; ++q)
        aP[RS][q] = __builtin_nontemporal_load(
          (const f32x4*)((const float*)Asrc + (size_t)q * 16384 * 256 + arow * (size_t)Kd + (k0 + cA * 4)));
    } else {
      aB[RS] = *(const s16x4*)((const unsigned short*)Asrc + arow * (size_t)Kd + (k0 + cA * 4));
    }
    #pragma unroll
    for (int i = 0; i < BITER; ++i)
      bRg[RS][i] = *(const s16x8*)(Bsrc + (size_t)(rB + i * 64) * Kd + (k0 + cB * 8));
  };

  auto writeAB = [&](auto rsc, int buf){
    constexpr int RS = decltype(rsc)::v;
    s16x4 w;
    if constexpr (AMODE == 3){
      #pragma unroll
      for (int e = 0; e < 4; ++e)
        w[e] = (short)f2bf(aP[RS][0][e] + aP[RS][1][e] + aP[RS][2][e] + aP[RS][3][e]);
    } else {
      w = aB[RS];
    }
    *(s16x4*)&Alds[buf][rA * 64 + ((((cA >> 1) ^ (rA & 7)) * 8) + (cA & 1) * 4)] = w;
    #pragma unroll
    for (int i = 0; i < BITER; ++i){
      int r = rB + i * 64;
      *(s16x8*)&Blds[buf][r * 64 + ((cB ^ (r & 7)) * 8)] = bRg[RS][i];
    }
  };

  auto compute = [&](int buf){
    s16x8 af[2]; s16x8 bfr[NF][2];
    #pragma unroll
    for (int k = 0; k < 2; ++k){
      int row = wm * 16 + fr;
      int c = k * 4 + fq;
      af[k] = *(const s16x8*)&Alds[buf][row * 64 + ((c ^ (row & 7)) * 8)];
    }
    #pragma unroll
    for (int n = 0; n < NF; ++n)
      #pragma unroll
      for (int k = 0; k < 2; ++k){
        int col = wn * (BN / 4) + n * 16 + fr;
        int c = k * 4 + fq;
        bfr[n][k] = *(const s16x8*)&Blds[buf][col * 64 + ((c ^ (col & 7)) * 8)];
      }
    #pragma unroll
    for (int k = 0; k < 2; ++k)
      #pragma unroll
      for (int n = 0; n < NF; ++n)
        acc[n] = __builtin_amdgcn_mfma_f32_16x16x32_bf16(af[k], bfr[n][k], acc[n], 0, 0, 0);
  };

  const int nsteps = Kd / 64;
  loadAB(IC<0>{}, 0);
  loadAB(IC<1>{}, 64);
  writeAB(IC<0>{}, 0);
  __syncthreads();

  for (int s = 0; s < nsteps; s += 2){
    if (s + 2 < nsteps) loadAB(IC<0>{}, (s + 2) * 64);
    compute(0);
    if (s + 1 < nsteps) writeAB(IC<1>{}, 1);
    __syncthreads();
    if (s + 3 < nsteps) loadAB(IC<1>{}, (s + 3) * 64);
    compute(1);
    if (s + 2 < nsteps) writeAB(IC<0>{}, 0);
    __syncthreads();
  }

  {
    int rowb = row0 + wm * 16 + fq * 4;
    #pragma unroll
    for (int n = 0; n < NF; ++n){
      int col = wn * (BN / 4) + n * 16 + fr;
      f32x4 v = acc[n];
      float b = bias[col];
      if constexpr (EPI == 1){
        u16x4 w;
        #pragma unroll
        for (int j = 0; j < 4; ++j) w[j] = f2bf(fmaxf(v[j] + b, 0.f));
        *(u16x4*)((unsigned short*)Cdst + (size_t)col * M + rowb) = w;
      } else if constexpr (EPI == 2){
        unsigned short* o = (unsigned short*)Cdst;
        #pragma unroll
        for (int j = 0; j < 4; ++j) o[(size_t)(rowb + j) * BN + col] = f2bf(fmaxf(v[j] + b, 0.f));
      } else {
        float* o = (float*)Cdst;
        #pragma unroll
        for (int j = 0; j < 4; ++j) o[(size_t)(rowb + j) * BN + col] = fmaxf(v[j] + b, 0.f);
      }
    }
  }
}

// out[i] = softmax(encode[i] @ W2^T + b2), one wave per row
__global__ void mlp2_k(const float* __restrict__ enc, const float* __restrict__ W2,
                       const float* __restrict__ b2, float* __restrict__ out){
  int gw = (int)((blockIdx.x * blockDim.x + threadIdx.x) >> 6);
  int lane = threadIdx.x & 63;
  if (gw >= 8192) return;
  int c = lane & 15, q = lane >> 4;
  const float* e = enc + (size_t)gw * 128 + q * 32;
  const float* w = W2 + c * 128 + q * 32;
  float s = 0.f;
  #pragma unroll
  for (int k = 0; k < 32; ++k) s += e[k] * w[k];
  s += __shfl_xor(s, 16);
  s += __shfl_xor(s, 32);
  s += b2[c];
  float mx = s;
  #pragma unroll
  for (int d = 1; d < 16; d <<= 1) mx = fmaxf(mx, __shfl_xor(mx, d));
  float ex = __expf(s - mx);
  float sm = ex;
  #pragma unroll
  for (int d = 1; d < 16; d <<= 1) sm += __shfl_xor(sm, d);
  float r = ex / sm;
  if (q == 0) out[(size_t)gw * 16 + c] = r;
}

extern "C" void kernel_launch(void* const* d_in, const int* in_sizes, int n_in,
                              void* d_out, int out_size, void* d_ws, size_t ws_size,
                              hipStream_t stream) {
  const float* A  = (const float*)d_in[0];   // [16384,16384]
  const float* x0 = (const float*)d_in[1];   // [16384,256]
  const float* gw = (const float*)d_in[2];   // [3,256,256]
  const float* gb = (const float*)d_in[3];   // [3,256]
  const float* w1 = (const float*)d_in[4];   // [128,256]
  const float* b1 = (const float*)d_in[5];   // [128]
  const float* w2 = (const float*)d_in[6];   // [16,128]
  const float* b2 = (const float*)d_in[7];   // [16]
  const int*  idx = (const int*)d_in[8];     // [8192]
  float* out = (float*)d_out;

  char* ws = (char*)d_ws;
  unsigned short* Abf = (unsigned short*)ws;                        // 16384^2 bf16 (512 MiB)
  float*          P   = (float*)(ws + (512u << 20));                // 4 x 16384*256 f32 (64 MiB)
  unsigned short* xbT = (unsigned short*)(ws + (576u << 20));       // 256*16384 bf16 (8 MiB)
  unsigned short* x3b = (unsigned short*)(ws + (584u << 20));       // 16384*256 bf16 (8 MiB)
  unsigned short* wgb = (unsigned short*)(ws + (592u << 20));       // 3*256*256 bf16
  unsigned short* w1b = (unsigned short*)(ws + (592u << 20) + 3 * 65536 * 2); // 128*256 bf16

  xpose_cvt<<<dim3(256, 4), 256, 0, stream>>>(x0, xbT);
  cvt_k<<<192, 256, 0, stream>>>(gw, wgb, 3 * 65536);
  cvt_k<<<32, 256, 0, stream>>>(w1, w1b, 128 * 256);

  // layer 0: P = A @ X (split-K=4, fp32 A converted + persisted to Abf)
  gemmA_k<0><<<512, 512, 0, stream>>>(A, xbT, P, Abf);
  gemm_k<256, 3, 1><<<512, 512, 0, stream>>>(P, wgb + 0 * 65536, gb + 0 * 256, nullptr, xbT, 16384, 256);
  // layer 1
  gemmA_k<1><<<512, 512, 0, stream>>>(Abf, xbT, P, nullptr);
  gemm_k<256, 3, 1><<<512, 512, 0, stream>>>(P, wgb + 1 * 65536, gb + 1 * 256, nullptr, xbT, 16384, 256);
  // layer 2: x3 = relu((P0+P1+P2+P3) @ W_2^T + b_2), row-major bf16
  gemmA_k<1><<<512, 512, 0, stream>>>(Abf, xbT, P, nullptr);
  // ---- MEASUREMENT (round 9 only): 10 idempotent replicas of the bf16 big GEMM.
  // dur_us = base(826) + 10 * T(gemmA_k<1>). Deterministic: rewrites identical P.
  for (int r = 0; r < 10; ++r)
    gemmA_k<1><<<512, 512, 0, stream>>>(Abf, xbT, P, nullptr);
  gemm_k<256, 3, 2><<<512, 512, 0, stream>>>(P, wgb + 2 * 65536, gb + 2 * 256, nullptr, x3b, 16384, 256);
  // encode = relu(x3[idx] @ W1^T + b1) -> d_out fp32
  gemm_k<128, 2, 3><<<256, 512, 0, stream>>>(x3b, w1b, b1, idx, out, 8192, 256);
  // out = softmax(encode @ W2^T + b2)
  mlp2_k<<<2048, 256, 0, stream>>>(out, w2, b2, out + (size_t)8192 * 128);
}

// Round 10
// 920.290 us; speedup vs baseline: 2.5932x; 2.5932x over previous
//
#include <hip/hip_runtime.h>

typedef __attribute__((ext_vector_type(8))) short s16x8;
typedef __attribute__((ext_vector_type(4))) short s16x4;
typedef __attribute__((ext_vector_type(4))) float f32x4;
typedef __attribute__((ext_vector_type(4))) unsigned short u16x4;

template<int V> struct IC { static constexpr int v = V; };

__device__ __forceinline__ unsigned short f2bf(float f){
  unsigned u = __float_as_uint(f);
  u += 0x7fffu + ((u >> 16) & 1u);   // RNE
  return (unsigned short)(u >> 16);
}

// async global->LDS, 16B per lane (HW: wave-uniform LDS base + lane*16; per-lane GLOBAL addr).
__device__ __forceinline__ void gload16(const void* g, void* l){
  __builtin_amdgcn_global_load_lds((const __attribute__((address_space(1))) void*)g,
                                   (__attribute__((address_space(3))) void*)l, 16, 0, 0);
}

// x0 [16384,256] f32 -> XT [256,16384] bf16
__global__ void xpose_cvt(const float* __restrict__ src, unsigned short* __restrict__ dst){
  __shared__ float tile[64][65];
  const int R0 = blockIdx.x * 64;
  const int C0 = blockIdx.y * 64;
  const int t = threadIdx.x;
  #pragma unroll
  for (int i = 0; i < 16; ++i){
    int id = i * 256 + t; int r = id >> 6, c = id & 63;
    tile[r][c] = src[(size_t)(R0 + r) * 256 + (C0 + c)];
  }
  __syncthreads();
  #pragma unroll
  for (int i = 0; i < 16; ++i){
    int id = i * 256 + t; int c = id >> 6, r = id & 63;
    dst[(size_t)(C0 + c) * 16384 + (R0 + r)] = f2bf(tile[r][c]);
  }
}

__global__ void cvt_k(const float* __restrict__ src, unsigned short* __restrict__ dst, int n){
  int i = (blockIdx.x * 256 + threadIdx.x) * 4;
  if (i + 3 < n){
    f32x4 v = *(const f32x4*)(src + i);
    u16x4 o; o[0] = f2bf(v[0]); o[1] = f2bf(v[1]); o[2] = f2bf(v[2]); o[3] = f2bf(v[3]);
    *(u16x4*)(dst + i) = o;
  }
}

// ---------------- Big GEMM: P[kc] = A[16384,16384] @ X^T  (split-K=4) ----------------
// Counted-vmcnt double-buffered pipeline (T3/T4-lite): BM=128/BN=256/BK=64, 512 thr
// (8 waves 2m x 4n, wave tile 64x64), LDS 96 KiB (2 bufs) -> 1 block/CU.
// Per step: issue 6 DMAs for s+1 into buf^1; s_waitcnt vmcnt(6) (never 0 in loop);
// s_barrier; 32 MFMA; s_barrier. Next step's loads stay in flight across compute.
// Grid 512: xcd = b&7; kc = xcd>>1 (B-slice 2 MiB/XCD L2-resident); mi = (xcd&1)*64+(b>>3).
// XOR swizzle on GLOBAL source addr (scol = (lane&7)^srow), LDS linear, read with same XOR.
// AMODE 0: A fp32 reg-staged + T14 split (issue early / convert+ds_write after compute),
//          persists bf16 A to Aout.   AMODE 1: A bf16 via DMA.
template<int AMODE>
__global__ __launch_bounds__(512, 2)
void gemmA_k(const void* __restrict__ Asrc, const unsigned short* __restrict__ Bsrc,
             float* __restrict__ Pdst, unsigned short* __restrict__ Aout)
{
  __shared__ __align__(16) unsigned short Alds[2][128 * 64];
  __shared__ __align__(16) unsigned short Blds[2][256 * 64];

  const int tid  = threadIdx.x;
  const int lane = tid & 63;
  const int wv   = tid >> 6;
  const int wm   = wv >> 2;        // 0..1 (64 rows each)
  const int wn   = wv & 3;         // 0..3 (64 cols each)
  const int fr = lane & 15, fq = lane >> 4;

  const int b    = blockIdx.x;
  const int xcd  = b & 7;
  const int kc   = xcd >> 1;                    // 0..3
  const int mi   = ((xcd & 1) << 6) + (b >> 3); // 0..127
  const int row0 = mi * 128;
  const int kbase = kc * 4096;

  const int srow = lane >> 3;
  const int scol = (lane & 7) ^ srow;

  const unsigned short* Bg = Bsrc + (size_t)(wv * 32 + srow) * 16384 + kbase + scol * 8;
  const unsigned short* Ag = (AMODE == 1)
    ? (const unsigned short*)Asrc + (size_t)(row0 + wv * 16 + srow) * 16384 + kbase + scol * 8
    : nullptr;

  const int rS = tid >> 3;         // 0..63 (fp32 A staging row)
  const int cS = tid & 7;
  const float* Af32 = (const float*)Asrc;

  f32x4 acc[4][4];
  #pragma unroll
  for (int m = 0; m < 4; ++m)
    #pragma unroll
    for (int n = 0; n < 4; ++n)
      acc[m][n] = f32x4{0.f, 0.f, 0.f, 0.f};

  f32x4 aR[4];   // AMODE 0 in-flight A regs

  auto issueB = [&](int buf, int s){
    unsigned short* Bl = &Blds[buf][wv * 2048 + lane * 8];
    #pragma unroll
    for (int i = 0; i < 4; ++i)
      gload16(Bg + (size_t)i * 8 * 16384 + s * 64, Bl + i * 512);
  };
  auto issueA1 = [&](int buf, int s){
    unsigned short* Al = &Alds[buf][wv * 1024 + lane * 8];
    gload16(Ag + s * 64, Al);
    gload16(Ag + (size_t)8 * 16384 + s * 64, Al + 512);
  };
  auto issueA0 = [&](int s){
    const float* pa = Af32 + (size_t)(row0 + rS) * 16384 + kbase + s * 64 + cS * 8;
    const float* pb = pa + (size_t)64 * 16384;
    aR[0] = __builtin_nontemporal_load((const f32x4*)pa);
    aR[1] = __builtin_nontemporal_load((const f32x4*)(pa + 4));
    aR[2] = __builtin_nontemporal_load((const f32x4*)pb);
    aR[3] = __builtin_nontemporal_load((const f32x4*)(pb + 4));
  };
  auto writeA0 = [&](int buf, int s){
    s16x8 w0, w1;
    #pragma unroll
    for (int e = 0; e < 4; ++e){
      w0[e] = (short)f2bf(aR[0][e]); w0[e + 4] = (short)f2bf(aR[1][e]);
      w1[e] = (short)f2bf(aR[2][e]); w1[e + 4] = (short)f2bf(aR[3][e]);
    }
    *(s16x8*)&Alds[buf][rS * 64 + ((cS ^ (rS & 7)) * 8)] = w0;
    *(s16x8*)&Alds[buf][(rS + 64) * 64 + ((cS ^ (rS & 7)) * 8)] = w1;
    __builtin_nontemporal_store(w0, (s16x8*)&Aout[(size_t)(row0 + rS) * 16384 + kbase + s * 64 + cS * 8]);
    __builtin_nontemporal_store(w1, (s16x8*)&Aout[(size_t)(row0 + rS + 64) * 16384 + kbase + s * 64 + cS * 8]);
  };

  auto compute = [&](int buf){
    #pragma unroll
    for (int k = 0; k < 2; ++k){
      s16x8 af[4], bfr[4];
      const int c = k * 4 + fq;
      #pragma unroll
      for (int m = 0; m < 4; ++m){
        int row = wm * 64 + m * 16 + fr;
        af[m] = *(const s16x8*)&Alds[buf][row * 64 + ((c ^ (row & 7)) * 8)];
      }
      #pragma unroll
      for (int n = 0; n < 4; ++n){
        int col = wn * 64 + n * 16 + fr;
        bfr[n] = *(const s16x8*)&Blds[buf][col * 64 + ((c ^ (col & 7)) * 8)];
      }
      #pragma unroll
      for (int m = 0; m < 4; ++m)
        #pragma unroll
        for (int n = 0; n < 4; ++n)
          acc[m][n] = __builtin_amdgcn_mfma_f32_16x16x32_bf16(af[m], bfr[n], acc[m][n], 0, 0, 0);
    }
  };

  // ---- prologue: stage step 0 into buf 0
  if constexpr (AMODE == 0){
    issueA0(0);
    issueB(0, 0);
    writeA0(0, 0);          // compiler inserts the reg-dependency waits for aR
  } else {
    issueA1(0, 0);
    issueB(0, 0);
  }

  #pragma unroll 1
  for (int s = 0; s < 64; ++s){
    const int buf = s & 1;
    if constexpr (AMODE == 0){
      if (s + 1 < 64){
        issueA0(s + 1);           // A regs issued FIRST (older than B DMAs)
        issueB(buf ^ 1, s + 1);
        // outstanding: [B(s) x4][Aout st x2][A(s+1) x4][B(s+1) x4] -> wait leaves 10
        asm volatile("s_waitcnt vmcnt(10) lgkmcnt(0)" ::: "memory");
      } else {
        asm volatile("s_waitcnt vmcnt(0) lgkmcnt(0)" ::: "memory");
      }
      __builtin_amdgcn_s_barrier();
      compute(buf);
      if (s + 1 < 64) writeA0(buf ^ 1, s + 1);   // convert under cover; ds_write buf^1
      asm volatile("s_waitcnt lgkmcnt(0)" ::: "memory");
      __builtin_amdgcn_s_barrier();
    } else {
      if (s + 1 < 64){
        issueA1(buf ^ 1, s + 1);
        issueB(buf ^ 1, s + 1);
        asm volatile("s_waitcnt vmcnt(6)" ::: "memory");   // step-s DMAs done; 6 in flight
      } else {
        asm volatile("s_waitcnt vmcnt(0)" ::: "memory");
      }
      __builtin_amdgcn_s_barrier();
      compute(buf);
      __builtin_amdgcn_s_barrier();
    }
  }

  // epilogue: fp32 partial store (nt). C frag: col = lane&15, row = (lane>>4)*4 + j
  float* P = Pdst + (size_t)kc * 16384 * 256;
  #pragma unroll
  for (int m = 0; m < 4; ++m){
    int rowb = row0 + wm * 64 + m * 16 + fq * 4;
    #pragma unroll
    for (int n = 0; n < 4; ++n){
      int col = wn * 64 + n * 16 + fr;
      #pragma unroll
      for (int j = 0; j < 4; ++j)
        __builtin_nontemporal_store(acc[m][n][j], &P[(size_t)(rowb + j) * 256 + col]);
    }
  }
}

// ---------------- Small GEMM: C[M,BN] = A[M,Kd] @ B^T, BM=32 ----------------
// AMODE: 1 = A bf16 | 2 = A bf16 + gather | 3 = A = sum of 4 fp32 partials
// EPI: 1 = bias+relu bf16 TRANSPOSED | 2 = bias+relu bf16 row-major | 3 = bias+relu fp32
template<int BN, int AMODE, int EPI>
__global__ __launch_bounds__(512, 2)
void gemm_k(const void* __restrict__ Asrc, const unsigned short* __restrict__ Bsrc,
            const float* __restrict__ bias, const int* __restrict__ gidx,
            void* __restrict__ Cdst, const int M, const int Kd)
{
  constexpr int NF = BN / 64;
  constexpr int BITER = BN / 64;
  __shared__ __align__(16) unsigned short Alds[2][32 * 64];
  __shared__ __align__(16) unsigned short Blds[2][BN * 64];

  const int tid  = threadIdx.x;
  const int lane = tid & 63;
  const int wv   = tid >> 6;
  const int wm   = wv >> 2;
  const int wn   = wv & 3;
  const int row0 = blockIdx.x * 32;
  const int fr = lane & 15, fq = lane >> 4;

  const int rA = tid >> 4;         // 0..31
  const int cA = tid & 15;         // 4-elem chunk along K
  const int rB = tid >> 3;         // 0..63
  const int cB = tid & 7;          // 8-elem chunk along K

  size_t arow;
  if (AMODE == 2) arow = (size_t)gidx[row0 + rA];
  else            arow = (size_t)(row0 + rA);

  f32x4 acc[NF];
  #pragma unroll
  for (int n = 0; n < NF; ++n) acc[n] = f32x4{0.f, 0.f, 0.f, 0.f};

  f32x4 aP[2][4]; s16x4 aB[2]; s16x8 bRg[2][BITER];

  auto loadAB = [&](auto rsc, int k0){
    constexpr int RS = decltype(rsc)::v;
    if constexpr (AMODE == 3){
      #pragma unroll
      for (int q = 0; q < 4; ++q)
        aP[RS][q] = __builtin_nontemporal_load(
          (const f32x4*)((const float*)Asrc + (size_t)q * 16384 * 256 + arow * (size_t)Kd + (k0 + cA * 4)));
    } else {
      aB[RS] = *(const s16x4*)((const unsigned short*)Asrc + arow * (size_t)Kd + (k0 + cA * 4));
    }
    #pragma unroll
    for (int i = 0; i < BITER; ++i)
      bRg[RS][i] = *(const s16x8*)(Bsrc + (size_t)(rB + i * 64) * Kd + (k0 + cB * 8));
  };

  auto writeAB = [&](auto rsc, int buf){
    constexpr int RS = decltype(rsc)::v;
    s16x4 w;
    if constexpr (AMODE == 3){
      #pragma unroll
      for (int e = 0; e < 4; ++e)
        w[e] = (short)f2bf(aP[RS][0][e] + aP[RS][1][e] + aP[RS][2][e] + aP[RS][3][e]);
    } else {
      w = aB[RS];
    }
    *(s16x4*)&Alds[buf][rA * 64 + ((((cA >> 1) ^ (rA & 7)) * 8) + (cA & 1) * 4)] = w;
    #pragma unroll
    for (int i = 0; i < BITER; ++i){
      int r = rB + i * 64;
      *(s16x8*)&Blds[buf][r * 64 + ((cB ^ (r & 7)) * 8)] = bRg[RS][i];
    }
  };

  auto compute = [&](int buf){
    s16x8 af[2]; s16x8 bfr[NF][2];
    #pragma unroll
    for (int k = 0; k < 2; ++k){
      int row = wm * 16 + fr;
      int c = k * 4 + fq;
      af[k] = *(const s16x8*)&Alds[buf][row * 64 + ((c ^ (row & 7)) * 8)];
    }
    #pragma unroll
    for (int n = 0; n < NF; ++n)
      #pragma unroll
      for (int k = 0; k < 2; ++k){
        int col = wn * (BN / 4) + n * 16 + fr;
        int c = k * 4 + fq;
        bfr[n][k] = *(const s16x8*)&Blds[buf][col * 64 + ((c ^ (col & 7)) * 8)];
      }
    #pragma unroll
    for (int k = 0; k < 2; ++k)
      #pragma unroll
      for (int n = 0; n < NF; ++n)
        acc[n] = __builtin_amdgcn_mfma_f32_16x16x32_bf16(af[k], bfr[n][k], acc[n], 0, 0, 0);
  };

  const int nsteps = Kd / 64;
  loadAB(IC<0>{}, 0);
  loadAB(IC<1>{}, 64);
  writeAB(IC<0>{}, 0);
  __syncthreads();

  for (int s = 0; s < nsteps; s += 2){
    if (s + 2 < nsteps) loadAB(IC<0>{}, (s + 2) * 64);
    compute(0);
    if (s + 1 < nsteps) writeAB(IC<1>{}, 1);
    __syncthreads();
    if (s + 3 < nsteps) loadAB(IC<1>{}, (s + 3) * 64);
    compute(1);
    if (s + 2 < nsteps) writeAB(IC<0>{}, 0);
    __syncthreads();
  }

  {
    int rowb = row0 + wm * 16 + fq * 4;
    #pragma unroll
    for (int n = 0; n < NF; ++n){
      int col = wn * (BN / 4) + n * 16 + fr;
      f32x4 v = acc[n];
      float b = bias[col];
      if constexpr (EPI == 1){
        u16x4 w;
        #pragma unroll
        for (int j = 0; j < 4; ++j) w[j] = f2bf(fmaxf(v[j] + b, 0.f));
        *(u16x4*)((unsigned short*)Cdst + (size_t)col * M + rowb) = w;
      } else if constexpr (EPI == 2){
        unsigned short* o = (unsigned short*)Cdst;
        #pragma unroll
        for (int j = 0; j < 4; ++j) o[(size_t)(rowb + j) * BN + col] = f2bf(fmaxf(v[j] + b, 0.f));
      } else {
        float* o = (float*)Cdst;
        #pragma unroll
        for (int j = 0; j < 4; ++j) o[(size_t)(rowb + j) * BN + col] = fmaxf(v[j] + b, 0.f);
      }
    }
  }
}

// out[i] = softmax(encode[i] @ W2^T + b2), one wave per row
__global__ void mlp2_k(const float* __restrict__ enc, const float* __restrict__ W2,
                       const float* __restrict__ b2, float* __restrict__ out){
  int gw = (int)((blockIdx.x * blockDim.x + threadIdx.x) >> 6);
  int lane = threadIdx.x & 63;
  if (gw >= 8192) return;
  int c = lane & 15, q = lane >> 4;
  const float* e = enc + (size_t)gw * 128 + q * 32;
  const float* w = W2 + c * 128 + q * 32;
  float s = 0.f;
  #pragma unroll
  for (int k = 0; k < 32; ++k) s += e[k] * w[k];
  s += __shfl_xor(s, 16);
  s += __shfl_xor(s, 32);
  s += b2[c];
  float mx = s;
  #pragma unroll
  for (int d = 1; d < 16; d <<= 1) mx = fmaxf(mx, __shfl_xor(mx, d));
  float ex = __expf(s - mx);
  float sm = ex;
  #pragma unroll
  for (int d = 1; d < 16; d <<= 1) sm += __shfl_xor(sm, d);
  float r = ex / sm;
  if (q == 0) out[(size_t)gw * 16 + c] = r;
}

extern "C" void kernel_launch(void* const* d_in, const int* in_sizes, int n_in,
                              void* d_out, int out_size, void* d_ws, size_t ws_size,
                              hipStream_t stream) {
  const float* A  = (const float*)d_in[0];   // [16384,16384]
  const float* x0 = (const float*)d_in[1];   // [16384,256]
  const float* gw = (const float*)d_in[2];   // [3,256,256]
  const float* gb = (const float*)d_in[3];   // [3,256]
  const float* w1 = (const float*)d_in[4];   // [128,256]
  const float* b1 = (const float*)d_in[5];   // [128]
  const float* w2 = (const float*)d_in[6];   // [16,128]
  const float* b2 = (const float*)d_in[7];   // [16]
  const int*  idx = (const int*)d_in[8];     // [8192]
  float* out = (float*)d_out;

  char* ws = (char*)d_ws;
  unsigned short* Abf = (unsigned short*)ws;                        // 16384^2 bf16 (512 MiB)
  float*          P   = (float*)(ws + (512u << 20));                // 4 x 16384*256 f32 (64 MiB)
  unsigned short* xbT = (unsigned short*)(ws + (576u << 20));       // 256*16384 bf16 (8 MiB)
  unsigned short* x3b = (unsigned short*)(ws + (584u << 20));       // 16384*256 bf16 (8 MiB)
  unsigned short* wgb = (unsigned short*)(ws + (592u << 20));       // 3*256*256 bf16
  unsigned short* w1b = (unsigned short*)(ws + (592u << 20) + 3 * 65536 * 2); // 128*256 bf16

  xpose_cvt<<<dim3(256, 4), 256, 0, stream>>>(x0, xbT);
  cvt_k<<<192, 256, 0, stream>>>(gw, wgb, 3 * 65536);
  cvt_k<<<32, 256, 0, stream>>>(w1, w1b, 128 * 256);

  // layer 0: P = A @ X (split-K=4, fp32 A converted + persisted to Abf)
  gemmA_k<0><<<512, 512, 0, stream>>>(A, xbT, P, Abf);
  gemm_k<256, 3, 1><<<512, 512, 0, stream>>>(P, wgb + 0 * 65536, gb + 0 * 256, nullptr, xbT, 16384, 256);
  // layer 1
  gemmA_k<1><<<512, 512, 0, stream>>>(Abf, xbT, P, nullptr);
  gemm_k<256, 3, 1><<<512, 512, 0, stream>>>(P, wgb + 1 * 65536, gb + 1 * 256, nullptr, xbT, 16384, 256);
  // layer 2: x3 = relu((P0+P1+P2+P3) @ W_2^T + b_2), row-major bf16
  gemmA_k<1><<<512, 512, 0, stream>>>(Abf, xbT, P, nullptr);
  gemm_k<256, 3, 2><<<512, 512, 0, stream>>>(P, wgb + 2 * 65536, gb + 2 * 256, nullptr, x3b, 16384, 256);
  // encode = relu(x3[idx] @ W1^T + b1) -> d_out fp32
  gemm_k<128, 2, 3><<<256, 512, 0, stream>>>(x3b, w1b, b1, idx, out, 8192, 256);
  // out = softmax(encode @ W2^T + b2)
  mlp2_k<<<2048, 256, 0, stream>>>(out, w2, b2, out + (size_t)8192 * 128);
}

// Round 11
// 788.203 us; speedup vs baseline: 3.0277x; 1.1676x over previous
//
#include <hip/hip_runtime.h>

typedef __attribute__((ext_vector_type(8))) short s16x8;
typedef __attribute__((ext_vector_type(4))) short s16x4;
typedef __attribute__((ext_vector_type(4))) float f32x4;
typedef __attribute__((ext_vector_type(4))) unsigned short u16x4;

template<int V> struct IC { static constexpr int v = V; };

__device__ __forceinline__ unsigned short f2bf(float f){
  unsigned u = __float_as_uint(f);
  u += 0x7fffu + ((u >> 16) & 1u);   // RNE
  return (unsigned short)(u >> 16);
}

// async global->LDS, 16B per lane (wave-uniform LDS base + lane*16; per-lane GLOBAL addr).
__device__ __forceinline__ void gload16(const void* g, void* l){
  __builtin_amdgcn_global_load_lds((const __attribute__((address_space(1))) void*)g,
                                   (__attribute__((address_space(3))) void*)l, 16, 0, 0);
}

// x0 [16384,256] f32 -> XT [256,16384] bf16
__global__ void xpose_cvt(const float* __restrict__ src, unsigned short* __restrict__ dst){
  __shared__ float tile[64][65];
  const int R0 = blockIdx.x * 64;
  const int C0 = blockIdx.y * 64;
  const int t = threadIdx.x;
  #pragma unroll
  for (int i = 0; i < 16; ++i){
    int id = i * 256 + t; int r = id >> 6, c = id & 63;
    tile[r][c] = src[(size_t)(R0 + r) * 256 + (C0 + c)];
  }
  __syncthreads();
  #pragma unroll
  for (int i = 0; i < 16; ++i){
    int id = i * 256 + t; int c = id >> 6, r = id & 63;
    dst[(size_t)(C0 + c) * 16384 + (R0 + r)] = f2bf(tile[r][c]);
  }
}

__global__ void cvt_k(const float* __restrict__ src, unsigned short* __restrict__ dst, int n){
  int i = (blockIdx.x * 256 + threadIdx.x) * 4;
  if (i + 3 < n){
    f32x4 v = *(const f32x4*)(src + i);
    u16x4 o; o[0] = f2bf(v[0]); o[1] = f2bf(v[1]); o[2] = f2bf(v[2]); o[3] = f2bf(v[3]);
    *(u16x4*)(dst + i) = o;
  }
}

// ---- dedup chain: unique rows referenced by nodes_idx ----
__global__ void dedup_clear(int* flags, int* count){
  int i = blockIdx.x * 256 + threadIdx.x;
  if (i < 16384) flags[i] = 0;
  if (i == 0) *count = 0;
}
__global__ void dedup_mark(const int* __restrict__ idx, int* __restrict__ flags){
  int i = blockIdx.x * 256 + threadIdx.x;
  if (i < 8192) flags[idx[i]] = 1;          // racing stores of 1: benign
}
__global__ void dedup_compact(const int* __restrict__ flags, int* __restrict__ rank,
                              int* __restrict__ ulist, int* __restrict__ count){
  int i = blockIdx.x * 256 + threadIdx.x;
  if (i < 16384 && flags[i]){
    int r = atomicAdd(count, 1);
    rank[i] = r;
    ulist[r] = i;
  }
}
__global__ void dedup_remap(const int* __restrict__ idx, const int* __restrict__ rank,
                            int* __restrict__ gidx2){
  int i = blockIdx.x * 256 + threadIdx.x;
  if (i < 8192) gidx2[i] = rank[idx[i]];
}

// ---------------- Big GEMM: P[kc] = A @ X^T  (split-K=4) ----------------
// R8 proven structure: single-buffered LDS (48 KiB), BM=128/BN=256/BK=64, 512 thr
// (8 waves 2m x 4n, wave tile 64x64), 2 blocks/CU anti-phase, global_load_lds(16B),
// XOR swizzle on GLOBAL source addr, drain at syncthreads each step.
// AMODE 0: A fp32 reg-staged (convert + persist bf16 to Aout). grid 512.
// AMODE 1: A bf16 via DMA, all 16384 rows. grid 512.
// AMODE 2: A bf16 via DMA, GATHERED rows ulist[j] for j<nuniq; P rows j-indexed;
//          grid 256 (64 m-blocks x 4 kc over 8192 worst-case rows), early-exit.
template<int AMODE>
__global__ __launch_bounds__(512, 4)
void gemmA_k(const void* __restrict__ Asrc, const unsigned short* __restrict__ Bsrc,
             float* __restrict__ Pdst, unsigned short* __restrict__ Aout,
             const int* __restrict__ ulist, const int* __restrict__ pnuniq)
{
  __shared__ __align__(16) unsigned short Alds[128 * 64];
  __shared__ __align__(16) unsigned short Blds[256 * 64];

  const int tid  = threadIdx.x;
  const int lane = tid & 63;
  const int wv   = tid >> 6;
  const int wm   = wv >> 2;        // 0..1 (64 rows each)
  const int wn   = wv & 3;         // 0..3 (64 cols each)
  const int fr = lane & 15, fq = lane >> 4;

  const int b    = blockIdx.x;
  const int xcd  = b & 7;
  const int kc   = xcd >> 1;                    // 0..3
  const int mi   = (AMODE == 2) ? (((xcd & 1) << 5) + (b >> 3))   // 0..63
                                 : (((xcd & 1) << 6) + (b >> 3)); // 0..127
  const int row0 = mi * 128;
  const int kbase = kc * 4096;

  int nuniq = 0;
  if constexpr (AMODE == 2){
    nuniq = *pnuniq;
    if (row0 >= nuniq) return;     // block-uniform early exit, before any barrier
  }

  const int srow = lane >> 3;
  const int scol = (lane & 7) ^ srow;

  const unsigned short* Bg = Bsrc + (size_t)(wv * 32 + srow) * 16384 + kbase + scol * 8;
  unsigned short* Bl = &Blds[wv * 2048 + lane * 8];
  unsigned short* Al = &Alds[wv * 1024 + lane * 8];

  const unsigned short* Ag0 = nullptr;
  const unsigned short* Ag1 = nullptr;
  if constexpr (AMODE == 1){
    Ag0 = (const unsigned short*)Asrc + (size_t)(row0 + wv * 16 + srow) * 16384 + kbase + scol * 8;
    Ag1 = Ag0 + (size_t)8 * 16384;
  } else if constexpr (AMODE == 2){
    int j0 = row0 + wv * 16 + srow;
    int j1 = j0 + 8;
    int a0 = ulist[j0 < nuniq ? j0 : 0];
    int a1 = ulist[j1 < nuniq ? j1 : 0];
    Ag0 = (const unsigned short*)Asrc + (size_t)a0 * 16384 + kbase + scol * 8;
    Ag1 = (const unsigned short*)Asrc + (size_t)a1 * 16384 + kbase + scol * 8;
  }

  const int rS = tid >> 3;         // 0..63 (fp32 A staging row)
  const int cS = tid & 7;
  const float* Af32 = (const float*)Asrc;

  f32x4 acc[4][4];
  #pragma unroll
  for (int m = 0; m < 4; ++m)
    #pragma unroll
    for (int n = 0; n < 4; ++n)
      acc[m][n] = f32x4{0.f, 0.f, 0.f, 0.f};

  #pragma unroll 1
  for (int s = 0; s < 64; ++s){
    const int k0 = kbase + s * 64;
    if constexpr (AMODE == 0){
      const float* pa = Af32 + (size_t)(row0 + rS) * 16384 + k0 + cS * 8;
      const float* pb = pa + (size_t)64 * 16384;
      f32x4 a0 = __builtin_nontemporal_load((const f32x4*)pa);
      f32x4 a1 = __builtin_nontemporal_load((const f32x4*)(pa + 4));
      f32x4 a2 = __builtin_nontemporal_load((const f32x4*)pb);
      f32x4 a3 = __builtin_nontemporal_load((const f32x4*)(pb + 4));
      #pragma unroll
      for (int i = 0; i < 4; ++i)
        gload16(Bg + (size_t)i * 8 * 16384 + s * 64, Bl + i * 512);
      s16x8 w0, w1;
      #pragma unroll
      for (int e = 0; e < 4; ++e){
        w0[e] = (short)f2bf(a0[e]); w0[e + 4] = (short)f2bf(a1[e]);
        w1[e] = (short)f2bf(a2[e]); w1[e + 4] = (short)f2bf(a3[e]);
      }
      *(s16x8*)&Alds[rS * 64 + ((cS ^ (rS & 7)) * 8)] = w0;
      *(s16x8*)&Alds[(rS + 64) * 64 + ((cS ^ (rS & 7)) * 8)] = w1;
      __builtin_nontemporal_store(w0, (s16x8*)&Aout[(size_t)(row0 + rS) * 16384 + k0 + cS * 8]);
      __builtin_nontemporal_store(w1, (s16x8*)&Aout[(size_t)(row0 + rS + 64) * 16384 + k0 + cS * 8]);
    } else {
      gload16(Ag0 + s * 64, Al);
      gload16(Ag1 + s * 64, Al + 512);
      #pragma unroll
      for (int i = 0; i < 4; ++i)
        gload16(Bg + (size_t)i * 8 * 16384 + s * 64, Bl + i * 512);
    }
    __syncthreads();

    #pragma unroll
    for (int k = 0; k < 2; ++k){
      s16x8 af[4], bfr[4];
      const int c = k * 4 + fq;
      #pragma unroll
      for (int m = 0; m < 4; ++m){
        int row = wm * 64 + m * 16 + fr;
        af[m] = *(const s16x8*)&Alds[row * 64 + ((c ^ (row & 7)) * 8)];
      }
      #pragma unroll
      for (int n = 0; n < 4; ++n){
        int col = wn * 64 + n * 16 + fr;
        bfr[n] = *(const s16x8*)&Blds[col * 64 + ((c ^ (col & 7)) * 8)];
      }
      #pragma unroll
      for (int m = 0; m < 4; ++m)
        #pragma unroll
        for (int n = 0; n < 4; ++n)
          acc[m][n] = __builtin_amdgcn_mfma_f32_16x16x32_bf16(af[m], bfr[n], acc[m][n], 0, 0, 0);
    }
    __syncthreads();
  }

  float* P = Pdst + (size_t)kc * 16384 * 256;
  #pragma unroll
  for (int m = 0; m < 4; ++m){
    int rowb = row0 + wm * 64 + m * 16 + fq * 4;
    #pragma unroll
    for (int n = 0; n < 4; ++n){
      int col = wn * 64 + n * 16 + fr;
      #pragma unroll
      for (int j = 0; j < 4; ++j)
        __builtin_nontemporal_store(acc[m][n][j], &P[(size_t)(rowb + j) * 256 + col]);
    }
  }
}

// ---------------- Small GEMM: C[M,BN] = A[M,Kd] @ B^T, BM=32 ----------------
// AMODE: 1 = A bf16 | 2 = A bf16 + gather | 3 = A = sum of 4 fp32 partials
// EPI: 1 = bias+relu bf16 TRANSPOSED | 2 = bias+relu bf16 row-major | 3 = bias+relu fp32
template<int BN, int AMODE, int EPI>
__global__ __launch_bounds__(512, 2)
void gemm_k(const void* __restrict__ Asrc, const unsigned short* __restrict__ Bsrc,
            const float* __restrict__ bias, const int* __restrict__ gidx,
            void* __restrict__ Cdst, const int M, const int Kd)
{
  constexpr int NF = BN / 64;
  constexpr int BITER = BN / 64;
  __shared__ __align__(16) unsigned short Alds[2][32 * 64];
  __shared__ __align__(16) unsigned short Blds[2][BN * 64];

  const int tid  = threadIdx.x;
  const int lane = tid & 63;
  const int wv   = tid >> 6;
  const int wm   = wv >> 2;
  const int wn   = wv & 3;
  const int row0 = blockIdx.x * 32;
  const int fr = lane & 15, fq = lane >> 4;

  const int rA = tid >> 4;         // 0..31
  const int cA = tid & 15;         // 4-elem chunk along K
  const int rB = tid >> 3;         // 0..63
  const int cB = tid & 7;          // 8-elem chunk along K

  size_t arow;
  if (AMODE == 2) arow = (size_t)gidx[row0 + rA];
  else            arow = (size_t)(row0 + rA);

  f32x4 acc[NF];
  #pragma unroll
  for (int n = 0; n < NF; ++n) acc[n] = f32x4{0.f, 0.f, 0.f, 0.f};

  f32x4 aP[2][4]; s16x4 aB[2]; s16x8 bRg[2][BITER];

  auto loadAB = [&](auto rsc, int k0){
    constexpr int RS = decltype(rsc)::v;
    if constexpr (AMODE == 3){
      #pragma unroll
      for (int q = 0; q < 4; ++q)
        aP[RS][q] = __builtin_nontemporal_load(
          (const f32x4*)((const float*)Asrc + (size_t)q * 16384 * 256 + arow * (size_t)Kd + (k0 + cA * 4)));
    } else {
      aB[RS] = *(const s16x4*)((const unsigned short*)Asrc + arow * (size_t)Kd + (k0 + cA * 4));
    }
    #pragma unroll
    for (int i = 0; i < BITER; ++i)
      bRg[RS][i] = *(const s16x8*)(Bsrc + (size_t)(rB + i * 64) * Kd + (k0 + cB * 8));
  };

  auto writeAB = [&](auto rsc, int buf){
    constexpr int RS = decltype(rsc)::v;
    s16x4 w;
    if constexpr (AMODE == 3){
      #pragma unroll
      for (int e = 0; e < 4; ++e)
        w[e] = (short)f2bf(aP[RS][0][e] + aP[RS][1][e] + aP[RS][2][e] + aP[RS][3][e]);
    } else {
      w = aB[RS];
    }
    *(s16x4*)&Alds[buf][rA * 64 + ((((cA >> 1) ^ (rA & 7)) * 8) + (cA & 1) * 4)] = w;
    #pragma unroll
    for (int i = 0; i < BITER; ++i){
      int r = rB + i * 64;
      *(s16x8*)&Blds[buf][r * 64 + ((cB ^ (r & 7)) * 8)] = bRg[RS][i];
    }
  };

  auto compute = [&](int buf){
    s16x8 af[2]; s16x8 bfr[NF][2];
    #pragma unroll
    for (int k = 0; k < 2; ++k){
      int row = wm * 16 + fr;
      int c = k * 4 + fq;
      af[k] = *(const s16x8*)&Alds[buf][row * 64 + ((c ^ (row & 7)) * 8)];
    }
    #pragma unroll
    for (int n = 0; n < NF; ++n)
      #pragma unroll
      for (int k = 0; k < 2; ++k){
        int col = wn * (BN / 4) + n * 16 + fr;
        int c = k * 4 + fq;
        bfr[n][k] = *(const s16x8*)&Blds[buf][col * 64 + ((c ^ (col & 7)) * 8)];
      }
    #pragma unroll
    for (int k = 0; k < 2; ++k)
      #pragma unroll
      for (int n = 0; n < NF; ++n)
        acc[n] = __builtin_amdgcn_mfma_f32_16x16x32_bf16(af[k], bfr[n][k], acc[n], 0, 0, 0);
  };

  const int nsteps = Kd / 64;
  loadAB(IC<0>{}, 0);
  loadAB(IC<1>{}, 64);
  writeAB(IC<0>{}, 0);
  __syncthreads();

  for (int s = 0; s < nsteps; s += 2){
    if (s + 2 < nsteps) loadAB(IC<0>{}, (s + 2) * 64);
    compute(0);
    if (s + 1 < nsteps) writeAB(IC<1>{}, 1);
    __syncthreads();
    if (s + 3 < nsteps) loadAB(IC<1>{}, (s + 3) * 64);
    compute(1);
    if (s + 2 < nsteps) writeAB(IC<0>{}, 0);
    __syncthreads();
  }

  {
    int rowb = row0 + wm * 16 + fq * 4;
    #pragma unroll
    for (int n = 0; n < NF; ++n){
      int col = wn * (BN / 4) + n * 16 + fr;
      f32x4 v = acc[n];
      float b = bias[col];
      if constexpr (EPI == 1){
        u16x4 w;
        #pragma unroll
        for (int j = 0; j < 4; ++j) w[j] = f2bf(fmaxf(v[j] + b, 0.f));
        *(u16x4*)((unsigned short*)Cdst + (size_t)col * M + rowb) = w;
      } else if constexpr (EPI == 2){
        unsigned short* o = (unsigned short*)Cdst;
        #pragma unroll
        for (int j = 0; j < 4; ++j) o[(size_t)(rowb + j) * BN + col] = f2bf(fmaxf(v[j] + b, 0.f));
      } else {
        float* o = (float*)Cdst;
        #pragma unroll
        for (int j = 0; j < 4; ++j) o[(size_t)(rowb + j) * BN + col] = fmaxf(v[j] + b, 0.f);
      }
    }
  }
}

// out[i] = softmax(encode[i] @ W2^T + b2), one wave per row
__global__ void mlp2_k(const float* __restrict__ enc, const float* __restrict__ W2,
                       const float* __restrict__ b2, float* __restrict__ out){
  int gw = (int)((blockIdx.x * blockDim.x + threadIdx.x) >> 6);
  int lane = threadIdx.x & 63;
  if (gw >= 8192) return;
  int c = lane & 15, q = lane >> 4;
  const float* e = enc + (size_t)gw * 128 + q * 32;
  const float* w = W2 + c * 128 + q * 32;
  float s = 0.f;
  #pragma unroll
  for (int k = 0; k < 32; ++k) s += e[k] * w[k];
  s += __shfl_xor(s, 16);
  s += __shfl_xor(s, 32);
  s += b2[c];
  float mx = s;
  #pragma unroll
  for (int d = 1; d < 16; d <<= 1) mx = fmaxf(mx, __shfl_xor(mx, d));
  float ex = __expf(s - mx);
  float sm = ex;
  #pragma unroll
  for (int d = 1; d < 16; d <<= 1) sm += __shfl_xor(sm, d);
  float r = ex / sm;
  if (q == 0) out[(size_t)gw * 16 + c] = r;
}

extern "C" void kernel_launch(void* const* d_in, const int* in_sizes, int n_in,
                              void* d_out, int out_size, void* d_ws, size_t ws_size,
                              hipStream_t stream) {
  const float* A  = (const float*)d_in[0];   // [16384,16384]
  const float* x0 = (const float*)d_in[1];   // [16384,256]
  const float* gw = (const float*)d_in[2];   // [3,256,256]
  const float* gb = (const float*)d_in[3];   // [3,256]
  const float* w1 = (const float*)d_in[4];   // [128,256]
  const float* b1 = (const float*)d_in[5];   // [128]
  const float* w2 = (const float*)d_in[6];   // [16,128]
  const float* b2 = (const float*)d_in[7];   // [16]
  const int*  idx = (const int*)d_in[8];     // [8192]
  float* out = (float*)d_out;

  char* ws = (char*)d_ws;
  unsigned short* Abf = (unsigned short*)ws;                        // 16384^2 bf16 (512 MiB)
  float*          P   = (float*)(ws + (512u << 20));                // 4 x 16384*256 f32 (64 MiB)
  unsigned short* xbT = (unsigned short*)(ws + (576u << 20));       // 256*16384 bf16 (8 MiB)
  unsigned short* x3b = (unsigned short*)(ws + (584u << 20));       // 8192*256 bf16 (4 MiB used)
  unsigned short* wgb = (unsigned short*)(ws + (592u << 20));       // 3*256*256 bf16
  unsigned short* w1b = (unsigned short*)(ws + (592u << 20) + 3 * 65536 * 2); // 128*256 bf16
  int* flags = (int*)(ws + (600u << 20));                           // 16384 ints
  int* rank  = (int*)(ws + (600u << 20) + (64u << 10));             // 16384 ints
  int* ulist = (int*)(ws + (600u << 20) + (128u << 10));            // 8192 ints
  int* gidx2 = (int*)(ws + (600u << 20) + (160u << 10));            // 8192 ints
  int* ucnt  = (int*)(ws + (600u << 20) + (192u << 10));            // 1 int

  xpose_cvt<<<dim3(256, 4), 256, 0, stream>>>(x0, xbT);
  cvt_k<<<192, 256, 0, stream>>>(gw, wgb, 3 * 65536);
  cvt_k<<<32, 256, 0, stream>>>(w1, w1b, 128 * 256);
  dedup_clear<<<64, 256, 0, stream>>>(flags, ucnt);
  dedup_mark<<<32, 256, 0, stream>>>(idx, flags);
  dedup_compact<<<64, 256, 0, stream>>>(flags, rank, ulist, ucnt);
  dedup_remap<<<32, 256, 0, stream>>>(idx, rank, gidx2);

  // layer 0: P = A @ X (split-K=4, fp32 A converted + persisted to Abf)
  gemmA_k<0><<<512, 512, 0, stream>>>(A, xbT, P, Abf, nullptr, nullptr);
  gemm_k<256, 3, 1><<<512, 512, 0, stream>>>(P, wgb + 0 * 65536, gb + 0 * 256, nullptr, xbT, 16384, 256);
  // layer 1
  gemmA_k<1><<<512, 512, 0, stream>>>(Abf, xbT, P, nullptr, nullptr, nullptr);
  gemm_k<256, 3, 1><<<512, 512, 0, stream>>>(P, wgb + 1 * 65536, gb + 1 * 256, nullptr, xbT, 16384, 256);
  // layer 2: only unique gathered rows j -> P[.][j]; x3b[j] = relu((ΣP)[j] @ W2^T + b2)
  gemmA_k<2><<<256, 512, 0, stream>>>(Abf, xbT, P, nullptr, ulist, ucnt);
  gemm_k<256, 3, 2><<<256, 512, 0, stream>>>(P, wgb + 2 * 65536, gb + 2 * 256, nullptr, x3b, 8192, 256);
  // encode = relu(x3b[rank[idx]] @ W1^T + b1) -> d_out fp32
  gemm_k<128, 2, 3><<<256, 512, 0, stream>>>(x3b, w1b, b1, gidx2, out, 8192, 256);
  // out = softmax(encode @ W2^T + b2)
  mlp2_k<<<2048, 256, 0, stream>>>(out, w2, b2, out + (size_t)8192 * 128);
}